// Round 1
// baseline (3154.865 us; speedup 1.0000x reference)
//
#include <hip/hip_runtime.h>

// ---------------- copy (vectorized) ----------------
__global__ __launch_bounds__(256) void copy_f4(const float* __restrict__ in,
                                               float* __restrict__ out, int n4) {
    int i = blockIdx.x * 256 + threadIdx.x;
    if (i < n4) ((float4*)out)[i] = ((const float4*)in)[i];
}

// ---------------- scatter-add over edges ----------------
// z[dst] += h[src], DIN floats per edge; thread handles 4 dims.
template <int DIN>
__global__ __launch_bounds__(256) void scatter_add(const float* __restrict__ h,
                                                   const int* __restrict__ src,
                                                   const int* __restrict__ dst,
                                                   float* __restrict__ z, int E) {
    constexpr int CH = DIN / 4;           // chunks per edge
    constexpr int SH = (CH == 32) ? 5 : 4;
    int tid = blockIdx.x * 256 + threadIdx.x;
    if (tid >= E * CH) return;
    int e = tid >> SH;
    int q = tid & (CH - 1);
    int s = src[e], d = dst[e];
    const float4 v = *(const float4*)(h + (size_t)s * DIN + q * 4);
    float* zp = z + (size_t)d * DIN + q * 4;
    atomicAdd(zp + 0, v.x);
    atomicAdd(zp + 1, v.y);
    atomicAdd(zp + 2, v.z);
    atomicAdd(zp + 3, v.w);
}

// ---------------- fused 2-layer MLP + ReLU ----------------
// out[n] = relu( relu(z[n] @ W1 + b1) @ W2 + b2 ), thread-per-node.
// W1 staged [k][j], W2 staged transposed [j][k]; all lanes read the same LDS
// address (broadcast, conflict-free).
template <int DIN>
__global__ __launch_bounds__(256) void mlp_relu(const float* __restrict__ z,
                                                const float* __restrict__ W1,
                                                const float* __restrict__ b1,
                                                const float* __restrict__ W2,
                                                const float* __restrict__ b2,
                                                float* __restrict__ out, int n) {
    __shared__ float w1s[DIN * 64];
    __shared__ float w2t[64 * 64];
    __shared__ float b1s[64], b2s[64];
    for (int i = threadIdx.x; i < DIN * 64; i += 256) w1s[i] = W1[i];
    for (int i = threadIdx.x; i < 64 * 64; i += 256) {
        int k = i >> 6, j = i & 63;
        w2t[j * 64 + k] = W2[i];
    }
    if (threadIdx.x < 64) {
        b1s[threadIdx.x] = b1[threadIdx.x];
        b2s[threadIdx.x] = b2[threadIdx.x];
    }
    __syncthreads();
    int node = blockIdx.x * 256 + threadIdx.x;
    if (node >= n) return;

    float t[64];
#pragma unroll
    for (int j = 0; j < 64; j++) t[j] = b1s[j];

    const float* zr = z + (size_t)node * DIN;
#pragma unroll 2
    for (int k = 0; k < DIN; k += 4) {
        float4 zv4 = *(const float4*)(zr + k);
#pragma unroll
        for (int kk = 0; kk < 4; kk++) {
            float zv = (kk == 0) ? zv4.x : (kk == 1) ? zv4.y : (kk == 2) ? zv4.z : zv4.w;
            const float4* wr = (const float4*)&w1s[(k + kk) * 64];
#pragma unroll
            for (int j4 = 0; j4 < 16; j4++) {
                float4 w = wr[j4];
                t[j4 * 4 + 0] += zv * w.x;
                t[j4 * 4 + 1] += zv * w.y;
                t[j4 * 4 + 2] += zv * w.z;
                t[j4 * 4 + 3] += zv * w.w;
            }
        }
    }
#pragma unroll
    for (int j = 0; j < 64; j++) t[j] = fmaxf(t[j], 0.0f);

    float* orow = out + (size_t)node * 64;
#pragma unroll 1
    for (int j = 0; j < 64; j++) {
        float acc = b2s[j];
        const float4* wr = (const float4*)&w2t[j * 64];
#pragma unroll
        for (int k4 = 0; k4 < 16; k4++) {
            float4 w = wr[k4];
            acc += t[k4 * 4 + 0] * w.x + t[k4 * 4 + 1] * w.y +
                   t[k4 * 4 + 2] * w.z + t[k4 * 4 + 3] * w.w;
        }
        orow[j] = fmaxf(acc, 0.0f);
    }
}

// ---------------- mean pool (atomic) ----------------
__global__ __launch_bounds__(256) void pool_kernel(const float* __restrict__ h,
                                                   const int* __restrict__ batch,
                                                   float* __restrict__ sums,
                                                   int* __restrict__ cnt, int n) {
    int tid = blockIdx.x * 256 + threadIdx.x;
    if (tid >= n * 16) return;
    int node = tid >> 4, q = tid & 15;
    int b = batch[node];
    const float4 v = *(const float4*)(h + (size_t)node * 64 + q * 4);
    float* sp = sums + b * 64 + q * 4;
    atomicAdd(sp + 0, v.x);
    atomicAdd(sp + 1, v.y);
    atomicAdd(sp + 2, v.z);
    atomicAdd(sp + 3, v.w);
    if (q == 0) atomicAdd(&cnt[b], 1);
}

// ---------------- finalize: g = sums/cnt ; out = g @ Wl + bl ----------------
__global__ __launch_bounds__(64) void finalize_kernel(const float* __restrict__ sums,
                                                      const int* __restrict__ cnt,
                                                      const float* __restrict__ Wl,
                                                      const float* __restrict__ bl,
                                                      float* __restrict__ out, int G) {
    int g = blockIdx.x;
    int j = threadIdx.x;  // 64 threads
    __shared__ float gs[64];
    float c = (float)max(cnt[g], 1);
    float v = sums[g * 64 + j] / c;
    gs[j] = v;
    out[G * 2 + g * 64 + j] = v;  // g part, after out part (G*2 floats)
    __syncthreads();
    if (j < 2) {
        float acc = bl[j];
#pragma unroll
        for (int k = 0; k < 64; k++) acc += gs[k] * Wl[k * 2 + j];
        out[g * 2 + j] = acc;
    }
}

extern "C" void kernel_launch(void* const* d_in, const int* in_sizes, int n_in,
                              void* d_out, int out_size, void* d_ws, size_t ws_size,
                              hipStream_t stream) {
    const float* x     = (const float*)d_in[0];
    const int*   ei    = (const int*)d_in[1];
    const int*   batch = (const int*)d_in[2];
    const float* W1_0 = (const float*)d_in[3];
    const float* b1_0 = (const float*)d_in[4];
    const float* W2_0 = (const float*)d_in[5];
    const float* b2_0 = (const float*)d_in[6];
    const float* W1_1 = (const float*)d_in[7];
    const float* b1_1 = (const float*)d_in[8];
    const float* W2_1 = (const float*)d_in[9];
    const float* b2_1 = (const float*)d_in[10];
    const float* W1_2 = (const float*)d_in[11];
    const float* b1_2 = (const float*)d_in[12];
    const float* W2_2 = (const float*)d_in[13];
    const float* b2_2 = (const float*)d_in[14];
    const float* Wl   = (const float*)d_in[15];
    const float* bl   = (const float*)d_in[16];

    const int N = in_sizes[0] / 128;
    const int E = in_sizes[1] / 2;
    const int G = out_size / 66;  // out_size = G*2 + G*64
    const int* src = ei;
    const int* dst = ei + E;
    float* out = (float*)d_out;

    char* ws = (char*)d_ws;
    float* z    = (float*)ws;                                           // N*128
    float* hA   = (float*)(ws + (size_t)N * 128 * 4);                   // N*64
    float* hB   = (float*)(ws + (size_t)N * 128 * 4 + (size_t)N * 64 * 4);
    float* sums = (float*)(ws + (size_t)N * 128 * 4 + (size_t)N * 64 * 4 * 2);
    int*   cnt  = (int*)(sums + (size_t)G * 64);

    // ---- layer 0 (DIN=128) ----
    copy_f4<<<(N * 32 + 255) / 256, 256, 0, stream>>>(x, z, N * 32);
    scatter_add<128><<<(E * 32 + 255) / 256, 256, 0, stream>>>(x, src, dst, z, E);
    mlp_relu<128><<<(N + 255) / 256, 256, 0, stream>>>(z, W1_0, b1_0, W2_0, b2_0, hA, N);
    // ---- layer 1 (DIN=64) ----
    copy_f4<<<(N * 16 + 255) / 256, 256, 0, stream>>>(hA, z, N * 16);
    scatter_add<64><<<(E * 16 + 255) / 256, 256, 0, stream>>>(hA, src, dst, z, E);
    mlp_relu<64><<<(N + 255) / 256, 256, 0, stream>>>(z, W1_1, b1_1, W2_1, b2_1, hB, N);
    // ---- layer 2 (DIN=64) ----
    copy_f4<<<(N * 16 + 255) / 256, 256, 0, stream>>>(hB, z, N * 16);
    scatter_add<64><<<(E * 16 + 255) / 256, 256, 0, stream>>>(hB, src, dst, z, E);
    mlp_relu<64><<<(N + 255) / 256, 256, 0, stream>>>(z, W1_2, b1_2, W2_2, b2_2, hA, N);
    // ---- pool + head ----
    hipMemsetAsync(sums, 0, ((size_t)G * 64 + G) * 4, stream);
    pool_kernel<<<(N * 16 + 255) / 256, 256, 0, stream>>>(hA, batch, sums, cnt, N);
    finalize_kernel<<<G, 64, 0, stream>>>(sums, cnt, Wl, bl, out, G);
}

// Round 2
// 407.210 us; speedup vs baseline: 7.7475x; 7.7475x over previous
//
#include <hip/hip_runtime.h>

// ================= CSR build =================
__global__ __launch_bounds__(256) void hist_kernel(const int* __restrict__ dst,
                                                   int* __restrict__ deg, int E) {
    int e = blockIdx.x * 256 + threadIdx.x;
    if (e < E) atomicAdd(&deg[dst[e]], 1);
}

// block reduce: 1024 items per block
__global__ __launch_bounds__(256) void scan_reduce(const int* __restrict__ deg,
                                                   int* __restrict__ bsum, int n) {
    __shared__ int sdata[256];
    int base = blockIdx.x * 1024 + threadIdx.x * 4;
    int s = 0;
#pragma unroll
    for (int k = 0; k < 4; k++) { int i = base + k; if (i < n) s += deg[i]; }
    sdata[threadIdx.x] = s;
    __syncthreads();
    for (int off = 128; off > 0; off >>= 1) {
        if (threadIdx.x < off) sdata[threadIdx.x] += sdata[threadIdx.x + off];
        __syncthreads();
    }
    if (threadIdx.x == 0) bsum[blockIdx.x] = sdata[0];
}

__global__ void scan_bsum(int* __restrict__ bsum, int nb, int* __restrict__ rowptr, int n) {
    if (threadIdx.x == 0 && blockIdx.x == 0) {
        int acc = 0;
        for (int i = 0; i < nb; i++) { int v = bsum[i]; bsum[i] = acc; acc += v; }
        rowptr[n] = acc;
    }
}

__global__ __launch_bounds__(256) void scan_final(const int* __restrict__ deg,
                                                  const int* __restrict__ bsum,
                                                  int* __restrict__ rowptr, int n) {
    __shared__ int sdata[256];
    int t = threadIdx.x;
    int base = blockIdx.x * 1024 + t * 4;
    int v[4]; int s = 0;
#pragma unroll
    for (int k = 0; k < 4; k++) { int i = base + k; v[k] = (i < n) ? deg[i] : 0; s += v[k]; }
    sdata[t] = s;
    __syncthreads();
    for (int off = 1; off < 256; off <<= 1) {
        int x = 0;
        if (t >= off) x = sdata[t - off];
        __syncthreads();
        if (t >= off) sdata[t] += x;
        __syncthreads();
    }
    int off = bsum[blockIdx.x] + sdata[t] - s;  // exclusive offset for this thread
#pragma unroll
    for (int k = 0; k < 4; k++) {
        int i = base + k;
        if (i < n) { rowptr[i] = off; off += v[k]; }
    }
}

__global__ __launch_bounds__(256) void fill_col(const int* __restrict__ src,
                                                const int* __restrict__ dst,
                                                const int* __restrict__ rowptr,
                                                int* __restrict__ ctr,
                                                int* __restrict__ col, int E) {
    int e = blockIdx.x * 256 + threadIdx.x;
    if (e >= E) return;
    int d = dst[e];
    int p = rowptr[d] + atomicAdd(&ctr[d], 1);
    col[p] = src[e];
}

// ================= gather aggregation: z[i] = h[i] + sum_{j in N(i)} h[j] =================
template <int DIN>
__global__ __launch_bounds__(256) void gather_agg(const float* __restrict__ h,
                                                  const int* __restrict__ rowptr,
                                                  const int* __restrict__ col,
                                                  float* __restrict__ z, int n) {
    int node = (blockIdx.x * 256 + threadIdx.x) >> 6;
    int lane = threadIdx.x & 63;
    if (node >= n) return;
    int r0 = rowptr[node], r1 = rowptr[node + 1];
    if (DIN == 128) {
        float2 acc = *(const float2*)(h + (size_t)node * 128 + lane * 2);
        int e = r0;
        for (; e + 1 < r1; e += 2) {
            int c0 = col[e], c1 = col[e + 1];
            float2 v0 = *(const float2*)(h + (size_t)c0 * 128 + lane * 2);
            float2 v1 = *(const float2*)(h + (size_t)c1 * 128 + lane * 2);
            acc.x += v0.x + v1.x;
            acc.y += v0.y + v1.y;
        }
        if (e < r1) {
            float2 v = *(const float2*)(h + (size_t)col[e] * 128 + lane * 2);
            acc.x += v.x; acc.y += v.y;
        }
        *(float2*)(z + (size_t)node * 128 + lane * 2) = acc;
    } else {
        float acc = h[(size_t)node * 64 + lane];
        int e = r0;
        for (; e + 1 < r1; e += 2) {
            float v0 = h[(size_t)col[e] * 64 + lane];
            float v1 = h[(size_t)col[e + 1] * 64 + lane];
            acc += v0 + v1;
        }
        if (e < r1) acc += h[(size_t)col[e] * 64 + lane];
        z[(size_t)node * 64 + lane] = acc;
    }
}

// ================= fused 2-layer MLP + ReLU (thread-per-node) =================
template <int DIN>
__global__ __launch_bounds__(256) void mlp_relu(const float* __restrict__ z,
                                                const float* __restrict__ W1,
                                                const float* __restrict__ b1,
                                                const float* __restrict__ W2,
                                                const float* __restrict__ b2,
                                                float* __restrict__ out, int n) {
    __shared__ float w1s[DIN * 64];
    __shared__ float w2t[64 * 64];
    __shared__ float b1s[64], b2s[64];
    for (int i = threadIdx.x; i < DIN * 64; i += 256) w1s[i] = W1[i];
    for (int i = threadIdx.x; i < 64 * 64; i += 256) {
        int k = i >> 6, j = i & 63;
        w2t[j * 64 + k] = W2[i];
    }
    if (threadIdx.x < 64) {
        b1s[threadIdx.x] = b1[threadIdx.x];
        b2s[threadIdx.x] = b2[threadIdx.x];
    }
    __syncthreads();
    int node = blockIdx.x * 256 + threadIdx.x;
    if (node >= n) return;

    float t[64];
#pragma unroll
    for (int j = 0; j < 64; j++) t[j] = b1s[j];

    const float* zr = z + (size_t)node * DIN;
#pragma unroll 2
    for (int k = 0; k < DIN; k += 4) {
        float4 zv4 = *(const float4*)(zr + k);
#pragma unroll
        for (int kk = 0; kk < 4; kk++) {
            float zv = (kk == 0) ? zv4.x : (kk == 1) ? zv4.y : (kk == 2) ? zv4.z : zv4.w;
            const float4* wr = (const float4*)&w1s[(k + kk) * 64];
#pragma unroll
            for (int j4 = 0; j4 < 16; j4++) {
                float4 w = wr[j4];
                t[j4 * 4 + 0] += zv * w.x;
                t[j4 * 4 + 1] += zv * w.y;
                t[j4 * 4 + 2] += zv * w.z;
                t[j4 * 4 + 3] += zv * w.w;
            }
        }
    }
#pragma unroll
    for (int j = 0; j < 64; j++) t[j] = fmaxf(t[j], 0.0f);

    float* orow = out + (size_t)node * 64;
#pragma unroll 1
    for (int j = 0; j < 64; j++) {
        float acc = b2s[j];
        const float4* wr = (const float4*)&w2t[j * 64];
#pragma unroll
        for (int k4 = 0; k4 < 16; k4++) {
            float4 w = wr[k4];
            acc += t[k4 * 4 + 0] * w.x + t[k4 * 4 + 1] * w.y +
                   t[k4 * 4 + 2] * w.z + t[k4 * 4 + 3] * w.w;
        }
        orow[j] = fmaxf(acc, 0.0f);
    }
}

// ================= mean pool, exploiting sorted batch =================
// One wave (block=64) per 64 consecutive nodes; lane = dim. Run-length
// accumulate, flush one atomic per graph-id change.
__global__ __launch_bounds__(64) void pool_sorted(const float* __restrict__ h,
                                                  const int* __restrict__ batch,
                                                  float* __restrict__ sums,
                                                  int* __restrict__ cnt, int n) {
    int lane = threadIdx.x;
    int start = blockIdx.x * 64;
    int end = min(start + 64, n);
    if (start >= end) return;
    int cur = batch[start];
    float acc = 0.0f;
    int c = 0;
    for (int i = start; i < end; i++) {
        int b = batch[i];
        if (b != cur) {
            atomicAdd(&sums[cur * 64 + lane], acc);
            if (lane == 0) atomicAdd(&cnt[cur], c);
            acc = 0.0f; c = 0; cur = b;
        }
        acc += h[(size_t)i * 64 + lane];
        c++;
    }
    atomicAdd(&sums[cur * 64 + lane], acc);
    if (lane == 0) atomicAdd(&cnt[cur], c);
}

// ================= finalize: g = sums/cnt ; out = g @ Wl + bl =================
__global__ __launch_bounds__(64) void finalize_kernel(const float* __restrict__ sums,
                                                      const int* __restrict__ cnt,
                                                      const float* __restrict__ Wl,
                                                      const float* __restrict__ bl,
                                                      float* __restrict__ out, int G) {
    int g = blockIdx.x;
    int j = threadIdx.x;  // 64 threads
    __shared__ float gs[64];
    float c = (float)max(cnt[g], 1);
    float v = sums[g * 64 + j] / c;
    gs[j] = v;
    out[G * 2 + g * 64 + j] = v;
    __syncthreads();
    if (j < 2) {
        float acc = bl[j];
#pragma unroll
        for (int k = 0; k < 64; k++) acc += gs[k] * Wl[k * 2 + j];
        out[g * 2 + j] = acc;
    }
}

extern "C" void kernel_launch(void* const* d_in, const int* in_sizes, int n_in,
                              void* d_out, int out_size, void* d_ws, size_t ws_size,
                              hipStream_t stream) {
    const float* x     = (const float*)d_in[0];
    const int*   ei    = (const int*)d_in[1];
    const int*   batch = (const int*)d_in[2];
    const float* W1_0 = (const float*)d_in[3];
    const float* b1_0 = (const float*)d_in[4];
    const float* W2_0 = (const float*)d_in[5];
    const float* b2_0 = (const float*)d_in[6];
    const float* W1_1 = (const float*)d_in[7];
    const float* b1_1 = (const float*)d_in[8];
    const float* W2_1 = (const float*)d_in[9];
    const float* b2_1 = (const float*)d_in[10];
    const float* W1_2 = (const float*)d_in[11];
    const float* b1_2 = (const float*)d_in[12];
    const float* W2_2 = (const float*)d_in[13];
    const float* b2_2 = (const float*)d_in[14];
    const float* Wl   = (const float*)d_in[15];
    const float* bl   = (const float*)d_in[16];

    const int N = in_sizes[0] / 128;
    const int E = in_sizes[1] / 2;
    const int G = out_size / 66;
    const int* src = ei;
    const int* dst = ei + E;
    float* out = (float*)d_out;

    // ---- workspace layout ----
    float* z    = (float*)d_ws;                 // N*128
    float* hA   = z + (size_t)N * 128;          // N*64
    float* hB   = hA + (size_t)N * 64;          // N*64
    float* sums = hB + (size_t)N * 64;          // G*64
    int*   cnt  = (int*)(sums + (size_t)G * 64);// G
    int*   deg  = cnt + G;                      // N
    int*   ctr  = deg + N;                      // N
    int*   rowptr = ctr + N;                    // N+1
    int*   col  = rowptr + (N + 1);             // E
    int*   bsum = col + E;                      // nb

    const int nb = (N + 1023) / 1024;

    // ---- CSR build (per call; deterministic work) ----
    hipMemsetAsync(deg, 0, (size_t)N * 2 * sizeof(int), stream);  // deg + ctr
    hipMemsetAsync(sums, 0, ((size_t)G * 64 + G) * sizeof(float), stream);
    hist_kernel<<<(E + 255) / 256, 256, 0, stream>>>(dst, deg, E);
    scan_reduce<<<nb, 256, 0, stream>>>(deg, bsum, N);
    scan_bsum<<<1, 64, 0, stream>>>(bsum, nb, rowptr, N);
    scan_final<<<nb, 256, 0, stream>>>(deg, bsum, rowptr, N);
    fill_col<<<(E + 255) / 256, 256, 0, stream>>>(src, dst, rowptr, ctr, col, E);

    const int gwaves = (N * 64 + 255) / 256;

    // ---- layer 0 (DIN=128) ----
    gather_agg<128><<<gwaves, 256, 0, stream>>>(x, rowptr, col, z, N);
    mlp_relu<128><<<(N + 255) / 256, 256, 0, stream>>>(z, W1_0, b1_0, W2_0, b2_0, hA, N);
    // ---- layer 1 (DIN=64) ----
    gather_agg<64><<<gwaves, 256, 0, stream>>>(hA, rowptr, col, z, N);
    mlp_relu<64><<<(N + 255) / 256, 256, 0, stream>>>(z, W1_1, b1_1, W2_1, b2_1, hB, N);
    // ---- layer 2 (DIN=64) ----
    gather_agg<64><<<gwaves, 256, 0, stream>>>(hB, rowptr, col, z, N);
    mlp_relu<64><<<(N + 255) / 256, 256, 0, stream>>>(z, W1_2, b1_2, W2_2, b2_2, hA, N);
    // ---- pool + head ----
    pool_sorted<<<(N + 63) / 64, 64, 0, stream>>>(hA, batch, sums, cnt, N);
    finalize_kernel<<<G, 64, 0, stream>>>(sums, cnt, Wl, bl, out, G);
}

// Round 3
// 362.859 us; speedup vs baseline: 8.6945x; 1.1222x over previous
//
#include <hip/hip_runtime.h>

// ================= CSR build =================
__global__ __launch_bounds__(256) void hist_kernel(const int* __restrict__ dst,
                                                   int* __restrict__ deg, int E) {
    int e = blockIdx.x * 256 + threadIdx.x;
    if (e < E) atomicAdd(&deg[dst[e]], 1);
}

__global__ __launch_bounds__(256) void scan_reduce(const int* __restrict__ deg,
                                                   int* __restrict__ bsum, int n) {
    __shared__ int sdata[256];
    int base = blockIdx.x * 1024 + threadIdx.x * 4;
    int s = 0;
#pragma unroll
    for (int k = 0; k < 4; k++) { int i = base + k; if (i < n) s += deg[i]; }
    sdata[threadIdx.x] = s;
    __syncthreads();
    for (int off = 128; off > 0; off >>= 1) {
        if (threadIdx.x < off) sdata[threadIdx.x] += sdata[threadIdx.x + off];
        __syncthreads();
    }
    if (threadIdx.x == 0) bsum[blockIdx.x] = sdata[0];
}

__global__ void scan_bsum(int* __restrict__ bsum, int nb, int* __restrict__ rowptr, int n) {
    if (threadIdx.x == 0 && blockIdx.x == 0) {
        int acc = 0;
        for (int i = 0; i < nb; i++) { int v = bsum[i]; bsum[i] = acc; acc += v; }
        rowptr[n] = acc;
    }
}

__global__ __launch_bounds__(256) void scan_final(const int* __restrict__ deg,
                                                  const int* __restrict__ bsum,
                                                  int* __restrict__ rowptr, int n) {
    __shared__ int sdata[256];
    int t = threadIdx.x;
    int base = blockIdx.x * 1024 + t * 4;
    int v[4]; int s = 0;
#pragma unroll
    for (int k = 0; k < 4; k++) { int i = base + k; v[k] = (i < n) ? deg[i] : 0; s += v[k]; }
    sdata[t] = s;
    __syncthreads();
    for (int off = 1; off < 256; off <<= 1) {
        int x = 0;
        if (t >= off) x = sdata[t - off];
        __syncthreads();
        if (t >= off) sdata[t] += x;
        __syncthreads();
    }
    int off = bsum[blockIdx.x] + sdata[t] - s;
#pragma unroll
    for (int k = 0; k < 4; k++) {
        int i = base + k;
        if (i < n) { rowptr[i] = off; off += v[k]; }
    }
}

__global__ __launch_bounds__(256) void fill_col(const int* __restrict__ src,
                                                const int* __restrict__ dst,
                                                const int* __restrict__ rowptr,
                                                int* __restrict__ ctr,
                                                int* __restrict__ col, int E) {
    int e = blockIdx.x * 256 + threadIdx.x;
    if (e >= E) return;
    int d = dst[e];
    int p = rowptr[d] + atomicAdd(&ctr[d], 1);
    col[p] = src[e];
}

// ================= gather aggregation, 4 node-streams per wave =================
// z[i] = h[i] + sum_{j in N(i)} h[j].  16 lanes per node; lane covers
// DIN/16 floats (float4 or 2x float4). 4 independent edge loops per wave
// give ~8-16 outstanding loads (latency hiding), coalesced 256/512 B rows.
template <int DIN>
__global__ __launch_bounds__(256) void gather_agg4(const float* __restrict__ h,
                                                   const int* __restrict__ rowptr,
                                                   const int* __restrict__ col,
                                                   float* __restrict__ z, int n) {
    constexpr int VEC = DIN / 16;  // 4 (DIN=64) or 8 (DIN=128)
    int lane = threadIdx.x & 63;
    int sub = lane >> 4;
    int sl  = lane & 15;
    int node = blockIdx.x * 16 + (threadIdx.x >> 6) * 4 + sub;
    if (node >= n) return;
    int e  = rowptr[node];
    int e1 = rowptr[node + 1];

    const float* hp = h + (size_t)node * DIN + sl * VEC;
    float4 acc0 = *(const float4*)hp;
    float4 acc1;
    if (VEC == 8) acc1 = *(const float4*)(hp + 4);

    while (e + 1 < e1) {
        int c0 = col[e], c1 = col[e + 1];
        const float* p0 = h + (size_t)c0 * DIN + sl * VEC;
        const float* p1 = h + (size_t)c1 * DIN + sl * VEC;
        float4 v0 = *(const float4*)p0;
        float4 v1 = *(const float4*)p1;
        if (VEC == 8) {
            float4 w0 = *(const float4*)(p0 + 4);
            float4 w1 = *(const float4*)(p1 + 4);
            acc1.x += w0.x + w1.x; acc1.y += w0.y + w1.y;
            acc1.z += w0.z + w1.z; acc1.w += w0.w + w1.w;
        }
        acc0.x += v0.x + v1.x; acc0.y += v0.y + v1.y;
        acc0.z += v0.z + v1.z; acc0.w += v0.w + v1.w;
        e += 2;
    }
    if (e < e1) {
        int c0 = col[e];
        const float* p0 = h + (size_t)c0 * DIN + sl * VEC;
        float4 v0 = *(const float4*)p0;
        if (VEC == 8) {
            float4 w0 = *(const float4*)(p0 + 4);
            acc1.x += w0.x; acc1.y += w0.y; acc1.z += w0.z; acc1.w += w0.w;
        }
        acc0.x += v0.x; acc0.y += v0.y; acc0.z += v0.z; acc0.w += v0.w;
    }
    float* zp = z + (size_t)node * DIN + sl * VEC;
    *(float4*)zp = acc0;
    if (VEC == 8) *(float4*)(zp + 4) = acc1;
}

// ================= fused 2-layer MLP + ReLU (thread-per-node) =================
template <int DIN>
__global__ __launch_bounds__(256) void mlp_relu(const float* __restrict__ z,
                                                const float* __restrict__ W1,
                                                const float* __restrict__ b1,
                                                const float* __restrict__ W2,
                                                const float* __restrict__ b2,
                                                float* __restrict__ out, int n) {
    __shared__ float w1s[DIN * 64];
    __shared__ float w2t[64 * 64];
    __shared__ float b1s[64], b2s[64];
    for (int i = threadIdx.x; i < DIN * 64; i += 256) w1s[i] = W1[i];
    for (int i = threadIdx.x; i < 64 * 64; i += 256) {
        int k = i >> 6, j = i & 63;
        w2t[j * 64 + k] = W2[i];
    }
    if (threadIdx.x < 64) {
        b1s[threadIdx.x] = b1[threadIdx.x];
        b2s[threadIdx.x] = b2[threadIdx.x];
    }
    __syncthreads();
    int node = blockIdx.x * 256 + threadIdx.x;
    if (node >= n) return;

    float t[64];
#pragma unroll
    for (int j = 0; j < 64; j++) t[j] = b1s[j];

    const float* zr = z + (size_t)node * DIN;
#pragma unroll 2
    for (int k = 0; k < DIN; k += 4) {
        float4 zv4 = *(const float4*)(zr + k);
#pragma unroll
        for (int kk = 0; kk < 4; kk++) {
            float zv = (kk == 0) ? zv4.x : (kk == 1) ? zv4.y : (kk == 2) ? zv4.z : zv4.w;
            const float4* wr = (const float4*)&w1s[(k + kk) * 64];
#pragma unroll
            for (int j4 = 0; j4 < 16; j4++) {
                float4 w = wr[j4];
                t[j4 * 4 + 0] += zv * w.x;
                t[j4 * 4 + 1] += zv * w.y;
                t[j4 * 4 + 2] += zv * w.z;
                t[j4 * 4 + 3] += zv * w.w;
            }
        }
    }
#pragma unroll
    for (int j = 0; j < 64; j++) t[j] = fmaxf(t[j], 0.0f);

    float* orow = out + (size_t)node * 64;
#pragma unroll 1
    for (int j = 0; j < 64; j++) {
        float acc = b2s[j];
        const float4* wr = (const float4*)&w2t[j * 64];
#pragma unroll
        for (int k4 = 0; k4 < 16; k4++) {
            float4 w = wr[k4];
            acc += t[k4 * 4 + 0] * w.x + t[k4 * 4 + 1] * w.y +
                   t[k4 * 4 + 2] * w.z + t[k4 * 4 + 3] * w.w;
        }
        orow[j] = fmaxf(acc, 0.0f);
    }
}

// ================= mean pool, exploiting sorted batch =================
__global__ __launch_bounds__(64) void pool_sorted(const float* __restrict__ h,
                                                  const int* __restrict__ batch,
                                                  float* __restrict__ sums,
                                                  int* __restrict__ cnt, int n) {
    int lane = threadIdx.x;
    int start = blockIdx.x * 64;
    int end = min(start + 64, n);
    if (start >= end) return;
    int cur = batch[start];
    float acc = 0.0f;
    int c = 0;
    for (int i = start; i < end; i++) {
        int b = batch[i];
        if (b != cur) {
            atomicAdd(&sums[cur * 64 + lane], acc);
            if (lane == 0) atomicAdd(&cnt[cur], c);
            acc = 0.0f; c = 0; cur = b;
        }
        acc += h[(size_t)i * 64 + lane];
        c++;
    }
    atomicAdd(&sums[cur * 64 + lane], acc);
    if (lane == 0) atomicAdd(&cnt[cur], c);
}

// ================= finalize =================
__global__ __launch_bounds__(64) void finalize_kernel(const float* __restrict__ sums,
                                                      const int* __restrict__ cnt,
                                                      const float* __restrict__ Wl,
                                                      const float* __restrict__ bl,
                                                      float* __restrict__ out, int G) {
    int g = blockIdx.x;
    int j = threadIdx.x;
    __shared__ float gs[64];
    float c = (float)max(cnt[g], 1);
    float v = sums[g * 64 + j] / c;
    gs[j] = v;
    out[G * 2 + g * 64 + j] = v;
    __syncthreads();
    if (j < 2) {
        float acc = bl[j];
#pragma unroll
        for (int k = 0; k < 64; k++) acc += gs[k] * Wl[k * 2 + j];
        out[g * 2 + j] = acc;
    }
}

extern "C" void kernel_launch(void* const* d_in, const int* in_sizes, int n_in,
                              void* d_out, int out_size, void* d_ws, size_t ws_size,
                              hipStream_t stream) {
    const float* x     = (const float*)d_in[0];
    const int*   ei    = (const int*)d_in[1];
    const int*   batch = (const int*)d_in[2];
    const float* W1_0 = (const float*)d_in[3];
    const float* b1_0 = (const float*)d_in[4];
    const float* W2_0 = (const float*)d_in[5];
    const float* b2_0 = (const float*)d_in[6];
    const float* W1_1 = (const float*)d_in[7];
    const float* b1_1 = (const float*)d_in[8];
    const float* W2_1 = (const float*)d_in[9];
    const float* b2_1 = (const float*)d_in[10];
    const float* W1_2 = (const float*)d_in[11];
    const float* b1_2 = (const float*)d_in[12];
    const float* W2_2 = (const float*)d_in[13];
    const float* b2_2 = (const float*)d_in[14];
    const float* Wl   = (const float*)d_in[15];
    const float* bl   = (const float*)d_in[16];

    const int N = in_sizes[0] / 128;
    const int E = in_sizes[1] / 2;
    const int G = out_size / 66;
    const int* src = ei;
    const int* dst = ei + E;
    float* out = (float*)d_out;

    // ---- workspace layout ----
    float* z    = (float*)d_ws;                 // N*128
    float* hA   = z + (size_t)N * 128;          // N*64
    float* hB   = hA + (size_t)N * 64;          // N*64
    float* sums = hB + (size_t)N * 64;          // G*64
    int*   cnt  = (int*)(sums + (size_t)G * 64);// G
    int*   deg  = cnt + G;                      // N
    int*   ctr  = deg + N;                      // N
    int*   rowptr = ctr + N;                    // N+1
    int*   col  = rowptr + (N + 1);             // E
    int*   bsum = col + E;                      // nb

    const int nb = (N + 1023) / 1024;

    // ---- CSR build ----
    hipMemsetAsync(deg, 0, (size_t)N * 2 * sizeof(int), stream);
    hipMemsetAsync(sums, 0, ((size_t)G * 64 + G) * sizeof(float), stream);
    hist_kernel<<<(E + 255) / 256, 256, 0, stream>>>(dst, deg, E);
    scan_reduce<<<nb, 256, 0, stream>>>(deg, bsum, N);
    scan_bsum<<<1, 64, 0, stream>>>(bsum, nb, rowptr, N);
    scan_final<<<nb, 256, 0, stream>>>(deg, bsum, rowptr, N);
    fill_col<<<(E + 255) / 256, 256, 0, stream>>>(src, dst, rowptr, ctr, col, E);

    const int gblocks = (N + 15) / 16;

    // ---- layer 0 (DIN=128) ----
    gather_agg4<128><<<gblocks, 256, 0, stream>>>(x, rowptr, col, z, N);
    mlp_relu<128><<<(N + 255) / 256, 256, 0, stream>>>(z, W1_0, b1_0, W2_0, b2_0, hA, N);
    // ---- layer 1 ----
    gather_agg4<64><<<gblocks, 256, 0, stream>>>(hA, rowptr, col, z, N);
    mlp_relu<64><<<(N + 255) / 256, 256, 0, stream>>>(z, W1_1, b1_1, W2_1, b2_1, hB, N);
    // ---- layer 2 ----
    gather_agg4<64><<<gblocks, 256, 0, stream>>>(hB, rowptr, col, z, N);
    mlp_relu<64><<<(N + 255) / 256, 256, 0, stream>>>(z, W1_2, b1_2, W2_2, b2_2, hA, N);
    // ---- pool + head ----
    pool_sorted<<<(N + 63) / 64, 64, 0, stream>>>(hA, batch, sums, cnt, N);
    finalize_kernel<<<G, 64, 0, stream>>>(sums, cnt, Wl, bl, out, G);
}

// Round 4
// 358.127 us; speedup vs baseline: 8.8093x; 1.0132x over previous
//
#include <hip/hip_runtime.h>

__device__ inline float bflo(unsigned int u) { return __uint_as_float(u << 16); }
__device__ inline float bfhi(unsigned int u) { return __uint_as_float(u & 0xFFFF0000u); }
__device__ inline unsigned short f2bf(float f) {
    unsigned int u = __float_as_uint(f);
    return (unsigned short)((u + 0x7FFFu + ((u >> 16) & 1u)) >> 16);
}

// ================= CSR build =================
__global__ __launch_bounds__(256) void hist_kernel(const int* __restrict__ dst,
                                                   int* __restrict__ deg, int E) {
    int e = blockIdx.x * 256 + threadIdx.x;
    if (e < E) atomicAdd(&deg[dst[e]], 1);
}

__global__ __launch_bounds__(256) void scan_reduce(const int* __restrict__ deg,
                                                   int* __restrict__ bsum, int n) {
    __shared__ int sdata[256];
    int base = blockIdx.x * 1024 + threadIdx.x * 4;
    int s = 0;
#pragma unroll
    for (int k = 0; k < 4; k++) { int i = base + k; if (i < n) s += deg[i]; }
    sdata[threadIdx.x] = s;
    __syncthreads();
    for (int off = 128; off > 0; off >>= 1) {
        if (threadIdx.x < off) sdata[threadIdx.x] += sdata[threadIdx.x + off];
        __syncthreads();
    }
    if (threadIdx.x == 0) bsum[blockIdx.x] = sdata[0];
}

__global__ void scan_bsum(int* __restrict__ bsum, int nb, int* __restrict__ rowptr, int n) {
    if (threadIdx.x == 0 && blockIdx.x == 0) {
        int acc = 0;
        for (int i = 0; i < nb; i++) { int v = bsum[i]; bsum[i] = acc; acc += v; }
        rowptr[n] = acc;
    }
}

__global__ __launch_bounds__(256) void scan_final(const int* __restrict__ deg,
                                                  const int* __restrict__ bsum,
                                                  int* __restrict__ rowptr, int n) {
    __shared__ int sdata[256];
    int t = threadIdx.x;
    int base = blockIdx.x * 1024 + t * 4;
    int v[4]; int s = 0;
#pragma unroll
    for (int k = 0; k < 4; k++) { int i = base + k; v[k] = (i < n) ? deg[i] : 0; s += v[k]; }
    sdata[t] = s;
    __syncthreads();
    for (int off = 1; off < 256; off <<= 1) {
        int x = 0;
        if (t >= off) x = sdata[t - off];
        __syncthreads();
        if (t >= off) sdata[t] += x;
        __syncthreads();
    }
    int off = bsum[blockIdx.x] + sdata[t] - s;
#pragma unroll
    for (int k = 0; k < 4; k++) {
        int i = base + k;
        if (i < n) { rowptr[i] = off; off += v[k]; }
    }
}

__global__ __launch_bounds__(256) void fill_col(const int* __restrict__ src,
                                                const int* __restrict__ dst,
                                                const int* __restrict__ rowptr,
                                                int* __restrict__ ctr,
                                                int* __restrict__ col, int E) {
    int e = blockIdx.x * 256 + threadIdx.x;
    if (e >= E) return;
    int d = dst[e];
    int p = rowptr[d] + atomicAdd(&ctr[d], 1);
    col[p] = src[e];
}

// ================= Y = h @ W1 (no bias), output bf16 =================
template <int DIN>
__global__ __launch_bounds__(256) void gemm_y(const float* __restrict__ h,
                                              const float* __restrict__ W1,
                                              unsigned short* __restrict__ Y, int n) {
    __shared__ float w1s[DIN * 64];
    for (int i = threadIdx.x; i < DIN * 64; i += 256) w1s[i] = W1[i];
    __syncthreads();
    int node = blockIdx.x * 256 + threadIdx.x;
    if (node >= n) return;
    float acc[64];
#pragma unroll
    for (int j = 0; j < 64; j++) acc[j] = 0.0f;
    const float* zr = h + (size_t)node * DIN;
#pragma unroll 2
    for (int k = 0; k < DIN; k += 4) {
        float4 zv4 = *(const float4*)(zr + k);
#pragma unroll
        for (int kk = 0; kk < 4; kk++) {
            float zv = (kk == 0) ? zv4.x : (kk == 1) ? zv4.y : (kk == 2) ? zv4.z : zv4.w;
            const float4* wr = (const float4*)&w1s[(k + kk) * 64];
#pragma unroll
            for (int j4 = 0; j4 < 16; j4++) {
                float4 w = wr[j4];
                acc[j4 * 4 + 0] += zv * w.x;
                acc[j4 * 4 + 1] += zv * w.y;
                acc[j4 * 4 + 2] += zv * w.z;
                acc[j4 * 4 + 3] += zv * w.w;
            }
        }
    }
    unsigned int* yr = (unsigned int*)(Y + (size_t)node * 64);
#pragma unroll
    for (int j = 0; j < 8; j++) {
        uint4 w;
        w.x = (unsigned int)f2bf(acc[j * 8 + 0]) | ((unsigned int)f2bf(acc[j * 8 + 1]) << 16);
        w.y = (unsigned int)f2bf(acc[j * 8 + 2]) | ((unsigned int)f2bf(acc[j * 8 + 3]) << 16);
        w.z = (unsigned int)f2bf(acc[j * 8 + 4]) | ((unsigned int)f2bf(acc[j * 8 + 5]) << 16);
        w.w = (unsigned int)f2bf(acc[j * 8 + 6]) | ((unsigned int)f2bf(acc[j * 8 + 7]) << 16);
        *(uint4*)(yr + j * 4) = w;
    }
}

// ================= gather aggregation on bf16 rows =================
// Z[i] = Y[i] + sum_{j in N(i)} Y[j], f32 accumulate. 8 node-streams per
// wave, 8 lanes/node, 16 B (8 bf16) per lane -> 128 B coalesced rows.
__global__ __launch_bounds__(256) void gather_bf16(const unsigned short* __restrict__ Y,
                                                   const int* __restrict__ rowptr,
                                                   const int* __restrict__ col,
                                                   float* __restrict__ Z, int n) {
    int lane = threadIdx.x & 63;
    int sub = lane >> 3;   // 8 nodes per wave
    int sl  = lane & 7;    // 8 lanes per node
    int node = blockIdx.x * 32 + (threadIdx.x >> 6) * 8 + sub;
    if (node >= n) return;
    int e  = rowptr[node];
    int e1 = rowptr[node + 1];

    float a[8];
    {
        uint4 v = *(const uint4*)(Y + (size_t)node * 64 + sl * 8);
        a[0] = bflo(v.x); a[1] = bfhi(v.x);
        a[2] = bflo(v.y); a[3] = bfhi(v.y);
        a[4] = bflo(v.z); a[5] = bfhi(v.z);
        a[6] = bflo(v.w); a[7] = bfhi(v.w);
    }
    while (e + 1 < e1) {
        int c0 = col[e], c1 = col[e + 1];
        uint4 v0 = *(const uint4*)(Y + (size_t)c0 * 64 + sl * 8);
        uint4 v1 = *(const uint4*)(Y + (size_t)c1 * 64 + sl * 8);
        a[0] += bflo(v0.x) + bflo(v1.x); a[1] += bfhi(v0.x) + bfhi(v1.x);
        a[2] += bflo(v0.y) + bflo(v1.y); a[3] += bfhi(v0.y) + bfhi(v1.y);
        a[4] += bflo(v0.z) + bflo(v1.z); a[5] += bfhi(v0.z) + bfhi(v1.z);
        a[6] += bflo(v0.w) + bflo(v1.w); a[7] += bfhi(v0.w) + bfhi(v1.w);
        e += 2;
    }
    if (e < e1) {
        uint4 v0 = *(const uint4*)(Y + (size_t)col[e] * 64 + sl * 8);
        a[0] += bflo(v0.x); a[1] += bfhi(v0.x);
        a[2] += bflo(v0.y); a[3] += bfhi(v0.y);
        a[4] += bflo(v0.z); a[5] += bfhi(v0.z);
        a[6] += bflo(v0.w); a[7] += bfhi(v0.w);
    }
    float* zp = Z + (size_t)node * 64 + sl * 8;
    *(float4*)zp       = make_float4(a[0], a[1], a[2], a[3]);
    *(float4*)(zp + 4) = make_float4(a[4], a[5], a[6], a[7]);
}

// ================= fused post-agg: t=relu(Z+b1); v=relu(t@W2+b2);
//                   HASNEXT: Yn = bf16(v @ Wn)   else: Hout = v (f32) =================
template <int HASNEXT>
__global__ __launch_bounds__(256) void fuse_post(const float* __restrict__ Z,
                                                 const float* __restrict__ b1,
                                                 const float* __restrict__ W2,
                                                 const float* __restrict__ b2,
                                                 const float* __restrict__ Wn,
                                                 unsigned short* __restrict__ Yn,
                                                 float* __restrict__ Hout, int n) {
    __shared__ float w2s[64 * 64];
    __shared__ float wns[HASNEXT ? 64 * 64 : 64];
    __shared__ float b1s[64], b2s[64];
    for (int i = threadIdx.x; i < 64 * 64; i += 256) {
        w2s[i] = W2[i];
        if (HASNEXT) wns[i] = Wn[i];
    }
    if (threadIdx.x < 64) {
        b1s[threadIdx.x] = b1[threadIdx.x];
        b2s[threadIdx.x] = b2[threadIdx.x];
    }
    __syncthreads();
    int node = blockIdx.x * 256 + threadIdx.x;
    if (node >= n) return;

    float t[64];
    const float* zr = Z + (size_t)node * 64;
#pragma unroll
    for (int k = 0; k < 64; k += 4) {
        float4 zv = *(const float4*)(zr + k);
        t[k + 0] = fmaxf(zv.x + b1s[k + 0], 0.0f);
        t[k + 1] = fmaxf(zv.y + b1s[k + 1], 0.0f);
        t[k + 2] = fmaxf(zv.z + b1s[k + 2], 0.0f);
        t[k + 3] = fmaxf(zv.w + b1s[k + 3], 0.0f);
    }
    float acc[64];
#pragma unroll
    for (int j = 0; j < 64; j++) acc[j] = b2s[j];
#pragma unroll 4
    for (int k = 0; k < 64; k++) {
        float zv = t[k];
        const float4* wr = (const float4*)&w2s[k * 64];
#pragma unroll
        for (int j4 = 0; j4 < 16; j4++) {
            float4 w = wr[j4];
            acc[j4 * 4 + 0] += zv * w.x;
            acc[j4 * 4 + 1] += zv * w.y;
            acc[j4 * 4 + 2] += zv * w.z;
            acc[j4 * 4 + 3] += zv * w.w;
        }
    }
#pragma unroll
    for (int j = 0; j < 64; j++) acc[j] = fmaxf(acc[j], 0.0f);

    if (HASNEXT) {
        float o[64];
#pragma unroll
        for (int j = 0; j < 64; j++) o[j] = 0.0f;
#pragma unroll 4
        for (int k = 0; k < 64; k++) {
            float zv = acc[k];
            const float4* wr = (const float4*)&wns[k * 64];
#pragma unroll
            for (int j4 = 0; j4 < 16; j4++) {
                float4 w = wr[j4];
                o[j4 * 4 + 0] += zv * w.x;
                o[j4 * 4 + 1] += zv * w.y;
                o[j4 * 4 + 2] += zv * w.z;
                o[j4 * 4 + 3] += zv * w.w;
            }
        }
        unsigned int* yr = (unsigned int*)(Yn + (size_t)node * 64);
#pragma unroll
        for (int j = 0; j < 8; j++) {
            uint4 w;
            w.x = (unsigned int)f2bf(o[j * 8 + 0]) | ((unsigned int)f2bf(o[j * 8 + 1]) << 16);
            w.y = (unsigned int)f2bf(o[j * 8 + 2]) | ((unsigned int)f2bf(o[j * 8 + 3]) << 16);
            w.z = (unsigned int)f2bf(o[j * 8 + 4]) | ((unsigned int)f2bf(o[j * 8 + 5]) << 16);
            w.w = (unsigned int)f2bf(o[j * 8 + 6]) | ((unsigned int)f2bf(o[j * 8 + 7]) << 16);
            *(uint4*)(yr + j * 4) = w;
        }
    } else {
        float* hr = Hout + (size_t)node * 64;
#pragma unroll
        for (int j = 0; j < 64; j += 4)
            *(float4*)(hr + j) = make_float4(acc[j], acc[j + 1], acc[j + 2], acc[j + 3]);
    }
}

// ================= mean pool, exploiting sorted batch =================
__global__ __launch_bounds__(64) void pool_sorted(const float* __restrict__ h,
                                                  const int* __restrict__ batch,
                                                  float* __restrict__ sums,
                                                  int* __restrict__ cnt, int n) {
    int lane = threadIdx.x;
    int start = blockIdx.x * 64;
    int end = min(start + 64, n);
    if (start >= end) return;
    int cur = batch[start];
    float acc = 0.0f;
    int c = 0;
    for (int i = start; i < end; i++) {
        int b = batch[i];
        if (b != cur) {
            atomicAdd(&sums[cur * 64 + lane], acc);
            if (lane == 0) atomicAdd(&cnt[cur], c);
            acc = 0.0f; c = 0; cur = b;
        }
        acc += h[(size_t)i * 64 + lane];
        c++;
    }
    atomicAdd(&sums[cur * 64 + lane], acc);
    if (lane == 0) atomicAdd(&cnt[cur], c);
}

// ================= finalize =================
__global__ __launch_bounds__(64) void finalize_kernel(const float* __restrict__ sums,
                                                      const int* __restrict__ cnt,
                                                      const float* __restrict__ Wl,
                                                      const float* __restrict__ bl,
                                                      float* __restrict__ out, int G) {
    int g = blockIdx.x;
    int j = threadIdx.x;
    __shared__ float gs[64];
    float c = (float)max(cnt[g], 1);
    float v = sums[g * 64 + j] / c;
    gs[j] = v;
    out[G * 2 + g * 64 + j] = v;
    __syncthreads();
    if (j < 2) {
        float acc = bl[j];
#pragma unroll
        for (int k = 0; k < 64; k++) acc += gs[k] * Wl[k * 2 + j];
        out[g * 2 + j] = acc;
    }
}

extern "C" void kernel_launch(void* const* d_in, const int* in_sizes, int n_in,
                              void* d_out, int out_size, void* d_ws, size_t ws_size,
                              hipStream_t stream) {
    const float* x     = (const float*)d_in[0];
    const int*   ei    = (const int*)d_in[1];
    const int*   batch = (const int*)d_in[2];
    const float* W1_0 = (const float*)d_in[3];
    const float* b1_0 = (const float*)d_in[4];
    const float* W2_0 = (const float*)d_in[5];
    const float* b2_0 = (const float*)d_in[6];
    const float* W1_1 = (const float*)d_in[7];
    const float* b1_1 = (const float*)d_in[8];
    const float* W2_1 = (const float*)d_in[9];
    const float* b2_1 = (const float*)d_in[10];
    const float* W1_2 = (const float*)d_in[11];
    const float* b1_2 = (const float*)d_in[12];
    const float* W2_2 = (const float*)d_in[13];
    const float* b2_2 = (const float*)d_in[14];
    const float* Wl   = (const float*)d_in[15];
    const float* bl   = (const float*)d_in[16];

    const int N = in_sizes[0] / 128;
    const int E = in_sizes[1] / 2;
    const int G = out_size / 66;
    const int* src = ei;
    const int* dst = ei + E;
    float* out = (float*)d_out;

    // ---- workspace layout ----
    float* Z    = (float*)d_ws;                   // N*64 f32
    float* H    = Z + (size_t)N * 64;             // N*64 f32
    unsigned short* Y = (unsigned short*)(H + (size_t)N * 64);  // N*64 bf16
    float* sums = (float*)(Y + (size_t)N * 64);   // G*64
    int*   cnt  = (int*)(sums + (size_t)G * 64);  // G
    int*   deg  = cnt + G;                        // N
    int*   ctr  = deg + N;                        // N
    int*   rowptr = ctr + N;                      // N+1
    int*   col  = rowptr + (N + 1);               // E
    int*   bsum = col + E;                        // nb

    const int nb = (N + 1023) / 1024;

    // ---- CSR build ----
    hipMemsetAsync(deg, 0, (size_t)N * 2 * sizeof(int), stream);
    hipMemsetAsync(sums, 0, ((size_t)G * 64 + G) * sizeof(float), stream);
    hist_kernel<<<(E + 255) / 256, 256, 0, stream>>>(dst, deg, E);
    scan_reduce<<<nb, 256, 0, stream>>>(deg, bsum, N);
    scan_bsum<<<1, 64, 0, stream>>>(bsum, nb, rowptr, N);
    scan_final<<<nb, 256, 0, stream>>>(deg, bsum, rowptr, N);
    fill_col<<<(E + 255) / 256, 256, 0, stream>>>(src, dst, rowptr, ctr, col, E);

    const int nblk = (N + 255) / 256;
    const int gblk = (N + 31) / 32;

    // ---- layer 0 ----
    gemm_y<128><<<nblk, 256, 0, stream>>>(x, W1_0, Y, N);
    gather_bf16<<<gblk, 256, 0, stream>>>(Y, rowptr, col, Z, N);
    fuse_post<1><<<nblk, 256, 0, stream>>>(Z, b1_0, W2_0, b2_0, W1_1, Y, nullptr, N);
    // ---- layer 1 ----
    gather_bf16<<<gblk, 256, 0, stream>>>(Y, rowptr, col, Z, N);
    fuse_post<1><<<nblk, 256, 0, stream>>>(Z, b1_1, W2_1, b2_1, W1_2, Y, nullptr, N);
    // ---- layer 2 ----
    gather_bf16<<<gblk, 256, 0, stream>>>(Y, rowptr, col, Z, N);
    fuse_post<0><<<nblk, 256, 0, stream>>>(Z, b1_2, W2_2, b2_2, nullptr, nullptr, H, N);
    // ---- pool + head ----
    pool_sorted<<<(N + 63) / 64, 64, 0, stream>>>(H, batch, sums, cnt, N);
    finalize_kernel<<<G, 64, 0, stream>>>(sums, cnt, Wl, bl, out, G);
}

// Round 5
// 227.095 us; speedup vs baseline: 13.8923x; 1.5770x over previous
//
#include <hip/hip_runtime.h>

typedef unsigned short ushort_t;
typedef __attribute__((ext_vector_type(8))) short short8;
typedef __attribute__((ext_vector_type(4))) float f32x4;

__device__ inline float bflo(unsigned int u) { return __uint_as_float(u << 16); }
__device__ inline float bfhi(unsigned int u) { return __uint_as_float(u & 0xFFFF0000u); }
__device__ inline unsigned short f2bf(float f) {
    unsigned int u = __float_as_uint(f);
    return (unsigned short)((u + 0x7FFFu + ((u >> 16) & 1u)) >> 16);
}

union U16B { uint4 u; short8 s; };

// ================= CSR build =================
__global__ __launch_bounds__(256) void hist_kernel(const int* __restrict__ dst,
                                                   int* __restrict__ deg, int E) {
    int e = blockIdx.x * 256 + threadIdx.x;
    if (e < E) atomicAdd(&deg[dst[e]], 1);
}

__global__ __launch_bounds__(256) void scan_reduce(const int* __restrict__ deg,
                                                   int* __restrict__ bsum, int n) {
    __shared__ int sdata[256];
    int base = blockIdx.x * 1024 + threadIdx.x * 4;
    int s = 0;
#pragma unroll
    for (int k = 0; k < 4; k++) { int i = base + k; if (i < n) s += deg[i]; }
    sdata[threadIdx.x] = s;
    __syncthreads();
    for (int off = 128; off > 0; off >>= 1) {
        if (threadIdx.x < off) sdata[threadIdx.x] += sdata[threadIdx.x + off];
        __syncthreads();
    }
    if (threadIdx.x == 0) bsum[blockIdx.x] = sdata[0];
}

__global__ void scan_bsum(int* __restrict__ bsum, int nb, int* __restrict__ rowptr, int n) {
    if (threadIdx.x == 0 && blockIdx.x == 0) {
        int acc = 0;
        for (int i = 0; i < nb; i++) { int v = bsum[i]; bsum[i] = acc; acc += v; }
        rowptr[n] = acc;
    }
}

__global__ __launch_bounds__(256) void scan_final(const int* __restrict__ deg,
                                                  const int* __restrict__ bsum,
                                                  int* __restrict__ rowptr, int n) {
    __shared__ int sdata[256];
    int t = threadIdx.x;
    int base = blockIdx.x * 1024 + t * 4;
    int v[4]; int s = 0;
#pragma unroll
    for (int k = 0; k < 4; k++) { int i = base + k; v[k] = (i < n) ? deg[i] : 0; s += v[k]; }
    sdata[t] = s;
    __syncthreads();
    for (int off = 1; off < 256; off <<= 1) {
        int x = 0;
        if (t >= off) x = sdata[t - off];
        __syncthreads();
        if (t >= off) sdata[t] += x;
        __syncthreads();
    }
    int off = bsum[blockIdx.x] + sdata[t] - s;
#pragma unroll
    for (int k = 0; k < 4; k++) {
        int i = base + k;
        if (i < n) { rowptr[i] = off; off += v[k]; }
    }
}

__global__ __launch_bounds__(256) void fill_col(const int* __restrict__ src,
                                                const int* __restrict__ dst,
                                                const int* __restrict__ rowptr,
                                                int* __restrict__ ctr,
                                                int* __restrict__ col, int E) {
    int e = blockIdx.x * 256 + threadIdx.x;
    if (e >= E) return;
    int d = dst[e];
    int p = rowptr[d] + atomicAdd(&ctr[d], 1);
    col[p] = src[e];
}

// ================= MFMA GEMM: Y = bf16(x @ W1), x f32 [n x 128] =================
// Tile 64 nodes/block, 4 waves; wave w handles rows w*16..w*16+15, all 64 cols.
// A-frag (16x16x32 bf16): row = lane&15, k = 8*(lane>>4)+j.
// B-frag: col = lane&15, k = 8*(lane>>4)+j. D: col = lane&15, row = 4*(lane>>4)+r.
__global__ __launch_bounds__(256) void gemm_y_mfma(const float* __restrict__ x,
                                                   const float* __restrict__ W1,
                                                   ushort_t* __restrict__ Y, int n) {
    __shared__ ushort_t w1f[4][4][64][8];   // [ks][ct][lane][j], 16 KB
    __shared__ ushort_t ybuf[64][72];       // 9.2 KB
    for (int i = threadIdx.x; i < 8192; i += 256) {
        int j = i & 7, lane = (i >> 3) & 63, ct = (i >> 9) & 3, ks = (i >> 11) & 3;
        int k = ks * 32 + ((lane >> 4) << 3) + j;
        int c = ct * 16 + (lane & 15);
        w1f[ks][ct][lane][j] = f2bf(W1[k * 64 + c]);
    }
    __syncthreads();
    int w = threadIdx.x >> 6, lane = threadIdx.x & 63;
    int row0 = blockIdx.x * 64;
    int arow = row0 + w * 16 + (lane & 15);
    if (arow >= n) arow = n - 1;
    const float* xr = x + (size_t)arow * 128;
    int k0base = (lane >> 4) << 3;

    f32x4 acc[4] = {{0,0,0,0},{0,0,0,0},{0,0,0,0},{0,0,0,0}};
#pragma unroll
    for (int ks = 0; ks < 4; ks++) {
        int k0 = ks * 32 + k0base;
        float4 aa = *(const float4*)(xr + k0);
        float4 ab = *(const float4*)(xr + k0 + 4);
        U16B af;
        af.u.x = (unsigned int)f2bf(aa.x) | ((unsigned int)f2bf(aa.y) << 16);
        af.u.y = (unsigned int)f2bf(aa.z) | ((unsigned int)f2bf(aa.w) << 16);
        af.u.z = (unsigned int)f2bf(ab.x) | ((unsigned int)f2bf(ab.y) << 16);
        af.u.w = (unsigned int)f2bf(ab.z) | ((unsigned int)f2bf(ab.w) << 16);
#pragma unroll
        for (int ct = 0; ct < 4; ct++) {
            short8 bf = *(const short8*)&w1f[ks][ct][lane][0];
            acc[ct] = __builtin_amdgcn_mfma_f32_16x16x32_bf16(af.s, bf, acc[ct], 0, 0, 0);
        }
    }
#pragma unroll
    for (int ct = 0; ct < 4; ct++)
#pragma unroll
        for (int r = 0; r < 4; r++)
            ybuf[w * 16 + ((lane >> 4) << 2) + r][ct * 16 + (lane & 15)] = f2bf(acc[ct][r]);
    __syncthreads();
    // coalesced store: thread t -> row t>>2, 16 bf16 segment (t&3)
    int row = threadIdx.x >> 2, seg = threadIdx.x & 3;
    if (row0 + row < n) {
        const uint4* p = (const uint4*)&ybuf[row][seg * 16];
        uint4 v0 = p[0], v1 = p[1];
        uint4* q = (uint4*)(Y + (size_t)(row0 + row) * 64 + seg * 16);
        q[0] = v0; q[1] = v1;
    }
}

// ================= gather aggregation on bf16 rows -> bf16 Z =================
__global__ __launch_bounds__(256) void gather_bf16(const ushort_t* __restrict__ Y,
                                                   const int* __restrict__ rowptr,
                                                   const int* __restrict__ col,
                                                   ushort_t* __restrict__ Z, int n) {
    int lane = threadIdx.x & 63;
    int sub = lane >> 3;
    int sl  = lane & 7;
    int node = blockIdx.x * 32 + (threadIdx.x >> 6) * 8 + sub;
    if (node >= n) return;
    int e  = rowptr[node];
    int e1 = rowptr[node + 1];

    float a[8];
    {
        uint4 v = *(const uint4*)(Y + (size_t)node * 64 + sl * 8);
        a[0] = bflo(v.x); a[1] = bfhi(v.x);
        a[2] = bflo(v.y); a[3] = bfhi(v.y);
        a[4] = bflo(v.z); a[5] = bfhi(v.z);
        a[6] = bflo(v.w); a[7] = bfhi(v.w);
    }
    while (e + 1 < e1) {
        int c0 = col[e], c1 = col[e + 1];
        uint4 v0 = *(const uint4*)(Y + (size_t)c0 * 64 + sl * 8);
        uint4 v1 = *(const uint4*)(Y + (size_t)c1 * 64 + sl * 8);
        a[0] += bflo(v0.x) + bflo(v1.x); a[1] += bfhi(v0.x) + bfhi(v1.x);
        a[2] += bflo(v0.y) + bflo(v1.y); a[3] += bfhi(v0.y) + bfhi(v1.y);
        a[4] += bflo(v0.z) + bflo(v1.z); a[5] += bfhi(v0.z) + bfhi(v1.z);
        a[6] += bflo(v0.w) + bflo(v1.w); a[7] += bfhi(v0.w) + bfhi(v1.w);
        e += 2;
    }
    if (e < e1) {
        uint4 v0 = *(const uint4*)(Y + (size_t)col[e] * 64 + sl * 8);
        a[0] += bflo(v0.x); a[1] += bfhi(v0.x);
        a[2] += bflo(v0.y); a[3] += bfhi(v0.y);
        a[4] += bflo(v0.z); a[5] += bfhi(v0.z);
        a[6] += bflo(v0.w); a[7] += bfhi(v0.w);
    }
    uint4 o;
    o.x = (unsigned int)f2bf(a[0]) | ((unsigned int)f2bf(a[1]) << 16);
    o.y = (unsigned int)f2bf(a[2]) | ((unsigned int)f2bf(a[3]) << 16);
    o.z = (unsigned int)f2bf(a[4]) | ((unsigned int)f2bf(a[5]) << 16);
    o.w = (unsigned int)f2bf(a[6]) | ((unsigned int)f2bf(a[7]) << 16);
    *(uint4*)(Z + (size_t)node * 64 + sl * 8) = o;
}

// ================= fused MLP via MFMA =================
// t = relu(Z + b1); v = relu(t @ W2 + b2);
// HASNEXT: Y = bf16(v @ Wn)  else: H = v (f32, direct stores)
template <int HASNEXT>
__global__ __launch_bounds__(256) void fuse_mfma(const ushort_t* __restrict__ Z,
                                                 const float* __restrict__ b1,
                                                 const float* __restrict__ W2,
                                                 const float* __restrict__ b2,
                                                 const float* __restrict__ Wn,
                                                 ushort_t* __restrict__ Yn,
                                                 float* __restrict__ Hout, int n) {
    __shared__ ushort_t w2f[2][4][64][8];               // 8 KB
    __shared__ ushort_t wnf[HASNEXT ? 2 : 1][4][64][8]; // 8 KB / 4 KB
    __shared__ ushort_t t2[64][72];                     // 9.2 KB
    __shared__ float b1s[64], b2s[64];
    for (int i = threadIdx.x; i < 4096; i += 256) {
        int j = i & 7, lane = (i >> 3) & 63, ct = (i >> 9) & 3, ks = (i >> 11) & 1;
        int k = ks * 32 + ((lane >> 4) << 3) + j;
        int c = ct * 16 + (lane & 15);
        w2f[ks][ct][lane][j] = f2bf(W2[k * 64 + c]);
        if (HASNEXT) wnf[ks][ct][lane][j] = f2bf(Wn[k * 64 + c]);
    }
    if (threadIdx.x < 64) { b1s[threadIdx.x] = b1[threadIdx.x]; b2s[threadIdx.x] = b2[threadIdx.x]; }
    __syncthreads();

    int w = threadIdx.x >> 6, lane = threadIdx.x & 63;
    int row0 = blockIdx.x * 64;
    int arow = row0 + w * 16 + (lane & 15);
    if (arow >= n) arow = n - 1;
    const ushort_t* zr = Z + (size_t)arow * 64;
    int k0base = (lane >> 4) << 3;

    f32x4 acc[4] = {{0,0,0,0},{0,0,0,0},{0,0,0,0},{0,0,0,0}};
#pragma unroll
    for (int ks = 0; ks < 2; ks++) {
        int k0 = ks * 32 + k0base;
        uint4 zv = *(const uint4*)(zr + k0);
        float e0 = fmaxf(bflo(zv.x) + b1s[k0 + 0], 0.0f);
        float e1 = fmaxf(bfhi(zv.x) + b1s[k0 + 1], 0.0f);
        float e2 = fmaxf(bflo(zv.y) + b1s[k0 + 2], 0.0f);
        float e3 = fmaxf(bfhi(zv.y) + b1s[k0 + 3], 0.0f);
        float e4 = fmaxf(bflo(zv.z) + b1s[k0 + 4], 0.0f);
        float e5 = fmaxf(bfhi(zv.z) + b1s[k0 + 5], 0.0f);
        float e6 = fmaxf(bflo(zv.w) + b1s[k0 + 6], 0.0f);
        float e7 = fmaxf(bfhi(zv.w) + b1s[k0 + 7], 0.0f);
        U16B af;
        af.u.x = (unsigned int)f2bf(e0) | ((unsigned int)f2bf(e1) << 16);
        af.u.y = (unsigned int)f2bf(e2) | ((unsigned int)f2bf(e3) << 16);
        af.u.z = (unsigned int)f2bf(e4) | ((unsigned int)f2bf(e5) << 16);
        af.u.w = (unsigned int)f2bf(e6) | ((unsigned int)f2bf(e7) << 16);
#pragma unroll
        for (int ct = 0; ct < 4; ct++) {
            short8 bf = *(const short8*)&w2f[ks][ct][lane][0];
            acc[ct] = __builtin_amdgcn_mfma_f32_16x16x32_bf16(af.s, bf, acc[ct], 0, 0, 0);
        }
    }

    int colb = lane & 15;
    if (HASNEXT) {
        // v -> LDS (bf16), transpose D-layout -> A-layout
#pragma unroll
        for (int ct = 0; ct < 4; ct++)
#pragma unroll
            for (int r = 0; r < 4; r++) {
                float v = fmaxf(acc[ct][r] + b2s[ct * 16 + colb], 0.0f);
                t2[w * 16 + ((lane >> 4) << 2) + r][ct * 16 + colb] = f2bf(v);
            }
        __syncthreads();
        f32x4 acc2[4] = {{0,0,0,0},{0,0,0,0},{0,0,0,0},{0,0,0,0}};
#pragma unroll
        for (int ks = 0; ks < 2; ks++) {
            short8 af2 = *(const short8*)&t2[w * 16 + (lane & 15)][ks * 32 + k0base];
#pragma unroll
            for (int ct = 0; ct < 4; ct++) {
                short8 bf = *(const short8*)&wnf[ks][ct][lane][0];
                acc2[ct] = __builtin_amdgcn_mfma_f32_16x16x32_bf16(af2, bf, acc2[ct], 0, 0, 0);
            }
        }
        __syncthreads();
#pragma unroll
        for (int ct = 0; ct < 4; ct++)
#pragma unroll
            for (int r = 0; r < 4; r++)
                t2[w * 16 + ((lane >> 4) << 2) + r][ct * 16 + colb] = f2bf(acc2[ct][r]);
        __syncthreads();
        int row = threadIdx.x >> 2, seg = threadIdx.x & 3;
        if (row0 + row < n) {
            const uint4* p = (const uint4*)&t2[row][seg * 16];
            uint4 v0 = p[0], v1 = p[1];
            uint4* q = (uint4*)(Yn + (size_t)(row0 + row) * 64 + seg * 16);
            q[0] = v0; q[1] = v1;
        }
    } else {
        // last layer: H = v, f32 direct stores (16-lane groups hit one 64B line)
#pragma unroll
        for (int ct = 0; ct < 4; ct++)
#pragma unroll
            for (int r = 0; r < 4; r++) {
                int row = row0 + w * 16 + ((lane >> 4) << 2) + r;
                if (row < n) {
                    float v = fmaxf(acc[ct][r] + b2s[ct * 16 + colb], 0.0f);
                    Hout[(size_t)row * 64 + ct * 16 + colb] = v;
                }
            }
    }
}

// ================= mean pool, exploiting sorted batch =================
__global__ __launch_bounds__(64) void pool_sorted(const float* __restrict__ h,
                                                  const int* __restrict__ batch,
                                                  float* __restrict__ sums,
                                                  int* __restrict__ cnt, int n) {
    int lane = threadIdx.x;
    int start = blockIdx.x * 64;
    int end = min(start + 64, n);
    if (start >= end) return;
    int cur = batch[start];
    float acc = 0.0f;
    int c = 0;
    for (int i = start; i < end; i++) {
        int b = batch[i];
        if (b != cur) {
            atomicAdd(&sums[cur * 64 + lane], acc);
            if (lane == 0) atomicAdd(&cnt[cur], c);
            acc = 0.0f; c = 0; cur = b;
        }
        acc += h[(size_t)i * 64 + lane];
        c++;
    }
    atomicAdd(&sums[cur * 64 + lane], acc);
    if (lane == 0) atomicAdd(&cnt[cur], c);
}

// ================= finalize =================
__global__ __launch_bounds__(64) void finalize_kernel(const float* __restrict__ sums,
                                                      const int* __restrict__ cnt,
                                                      const float* __restrict__ Wl,
                                                      const float* __restrict__ bl,
                                                      float* __restrict__ out, int G) {
    int g = blockIdx.x;
    int j = threadIdx.x;
    __shared__ float gs[64];
    float c = (float)max(cnt[g], 1);
    float v = sums[g * 64 + j] / c;
    gs[j] = v;
    out[G * 2 + g * 64 + j] = v;
    __syncthreads();
    if (j < 2) {
        float acc = bl[j];
#pragma unroll
        for (int k = 0; k < 64; k++) acc += gs[k] * Wl[k * 2 + j];
        out[g * 2 + j] = acc;
    }
}

extern "C" void kernel_launch(void* const* d_in, const int* in_sizes, int n_in,
                              void* d_out, int out_size, void* d_ws, size_t ws_size,
                              hipStream_t stream) {
    const float* x     = (const float*)d_in[0];
    const int*   ei    = (const int*)d_in[1];
    const int*   batch = (const int*)d_in[2];
    const float* W1_0 = (const float*)d_in[3];
    const float* b1_0 = (const float*)d_in[4];
    const float* W2_0 = (const float*)d_in[5];
    const float* b2_0 = (const float*)d_in[6];
    const float* W1_1 = (const float*)d_in[7];
    const float* b1_1 = (const float*)d_in[8];
    const float* W2_1 = (const float*)d_in[9];
    const float* b2_1 = (const float*)d_in[10];
    const float* W1_2 = (const float*)d_in[11];
    const float* b1_2 = (const float*)d_in[12];
    const float* W2_2 = (const float*)d_in[13];
    const float* b2_2 = (const float*)d_in[14];
    const float* Wl   = (const float*)d_in[15];
    const float* bl   = (const float*)d_in[16];

    const int N = in_sizes[0] / 128;
    const int E = in_sizes[1] / 2;
    const int G = out_size / 66;
    const int* src = ei;
    const int* dst = ei + E;
    float* out = (float*)d_out;

    // ---- workspace layout ----
    float* H    = (float*)d_ws;                       // N*64 f32
    ushort_t* Y = (ushort_t*)(H + (size_t)N * 64);    // N*64 bf16
    ushort_t* Z = Y + (size_t)N * 64;                 // N*64 bf16
    float* sums = (float*)(Z + (size_t)N * 64);       // G*64
    int*   cnt  = (int*)(sums + (size_t)G * 64);      // G
    int*   deg  = cnt + G;                            // N
    int*   ctr  = deg + N;                            // N
    int*   rowptr = ctr + N;                          // N+1
    int*   col  = rowptr + (N + 1);                   // E
    int*   bsum = col + E;                            // nb

    const int nb = (N + 1023) / 1024;

    // ---- CSR build ----
    hipMemsetAsync(deg, 0, (size_t)N * 2 * sizeof(int), stream);
    hipMemsetAsync(sums, 0, ((size_t)G * 64 + G) * sizeof(float), stream);
    hist_kernel<<<(E + 255) / 256, 256, 0, stream>>>(dst, deg, E);
    scan_reduce<<<nb, 256, 0, stream>>>(deg, bsum, N);
    scan_bsum<<<1, 64, 0, stream>>>(bsum, nb, rowptr, N);
    scan_final<<<nb, 256, 0, stream>>>(deg, bsum, rowptr, N);
    fill_col<<<(E + 255) / 256, 256, 0, stream>>>(src, dst, rowptr, ctr, col, E);

    const int mblk = (N + 63) / 64;
    const int gblk = (N + 31) / 32;

    // ---- layer 0 ----
    gemm_y_mfma<<<mblk, 256, 0, stream>>>(x, W1_0, Y, N);
    gather_bf16<<<gblk, 256, 0, stream>>>(Y, rowptr, col, Z, N);
    fuse_mfma<1><<<mblk, 256, 0, stream>>>(Z, b1_0, W2_0, b2_0, W1_1, Y, nullptr, N);
    // ---- layer 1 ----
    gather_bf16<<<gblk, 256, 0, stream>>>(Y, rowptr, col, Z, N);
    fuse_mfma<1><<<mblk, 256, 0, stream>>>(Z, b1_1, W2_1, b2_1, W1_2, Y, nullptr, N);
    // ---- layer 2 ----
    gather_bf16<<<gblk, 256, 0, stream>>>(Y, rowptr, col, Z, N);
    fuse_mfma<0><<<mblk, 256, 0, stream>>>(Z, b1_2, W2_2, b2_2, nullptr, nullptr, H, N);
    // ---- pool + head ----
    pool_sorted<<<(N + 63) / 64, 64, 0, stream>>>(H, batch, sums, cnt, N);
    finalize_kernel<<<G, 64, 0, stream>>>(sums, cnt, Wl, bl, out, G);
}